// Round 6
// baseline (478.965 us; speedup 1.0000x reference)
//
#include <hip/hip_runtime.h>
#include <hip/hip_bf16.h>
#include <hip/hip_cooperative_groups.h>

namespace cg = cooperative_groups;

typedef __attribute__((ext_vector_type(8))) short bhalf8;
typedef __attribute__((ext_vector_type(4))) float f32x4;

#define MFMA_BF16 __builtin_amdgcn_mfma_f32_16x16x32_bf16

namespace {

constexpr int   NPIX  = 16384;
constexpr int   NCH   = 64;          // 256-px chunks per batch
constexpr int   TILE  = 66 * 64;     // partial tile: 64 kv rows + t row + Sv row
constexpr float EPSV  = 1e-5f;
constexpr float INV64 = 1.0f / 64.0f;
constexpr float INV_N = 1.0f / 16384.0f;

__device__ __forceinline__ unsigned short f2bf(float f) {
    unsigned int u = __builtin_bit_cast(unsigned int, f);
    u += 0x7fffu + ((u >> 16) & 1u);
    return (unsigned short)(u >> 16);
}

union B8 { bhalf8 v; unsigned int u[4]; };

__device__ __forceinline__ unsigned int pk2(float a, float b) {
    union { __hip_bfloat162 h; unsigned int u; } x;
    x.h = __float22bfloat162_rn(float2{a, b});
    return x.u;
}

// ---------------------------------------------------------------------------
// One cooperative kernel, 5 phases separated by grid.sync().
// grid = 256 blocks (1 per CU) x 512 threads (8 waves).
// ---------------------------------------------------------------------------
__global__ __launch_bounds__(512, 2)
void fused(const float* __restrict__ v,
           const float* __restrict__ Wq, const float* __restrict__ bq,
           const float* __restrict__ Wk, const float* __restrict__ bk,
           const float* __restrict__ Wv, const float* __restrict__ bv,
           const float* __restrict__ lnqg, const float* __restrict__ lnqb,
           const float* __restrict__ lnkg, const float* __restrict__ lnkb,
           const float* __restrict__ Wo,  const float* __restrict__ Wob,
           float* __restrict__ out,
           float* __restrict__ part, float* __restrict__ s2buf,
           float* __restrict__ cbh,
           unsigned short* __restrict__ wkpk, unsigned short* __restrict__ wvpk,
           unsigned short* __restrict__ wqpk, unsigned short* __restrict__ wksumb,
           unsigned short* __restrict__ mpk)
{
    cg::grid_group grid = cg::this_grid();
    const int bid = blockIdx.x, t = threadIdx.x;

    __shared__ __align__(16) float smem[12864];   // 51.4 KB, phase-unioned

    // ======== P0: pack weight fragments + wksum ========
    if (bid < 96) {
        const int w = bid >> 5, sub = bid & 31, h = sub >> 2, nt = sub & 3;
        const float* W = (w == 0) ? Wk : (w == 1) ? Wv : Wq;
        unsigned short* dst = (w == 0) ? wkpk : (w == 1) ? wvpk : wqpk;
        if (t < 128) {
            const int ks = t >> 6, l = t & 63, g = l >> 4, m = l & 15;
            unsigned short tmp[8];
#pragma unroll
            for (int j = 0; j < 8; ++j)
                tmp[j] = f2bf(W[(size_t)(32 * ks + 8 * g + j) * 512 + h * 64 + 16 * nt + m]);
            unsigned short* d = dst + ((size_t)((h * 4 + nt) * 2 + ks)) * 512 + l * 8;
            *reinterpret_cast<ushort4*>(d)     = make_ushort4(tmp[0], tmp[1], tmp[2], tmp[3]);
            *reinterpret_cast<ushort4*>(d + 4) = make_ushort4(tmp[4], tmp[5], tmp[6], tmp[7]);
        }
    } else if (bid < 104) {
        const int h = bid - 96;
        if (t < 64) {
            float s = 0.f;
            const float* row = Wk + (size_t)t * 512 + h * 64;
#pragma unroll
            for (int d = 0; d < 64; ++d) s += row[d];
            wksumb[h * 64 + t] = f2bf(s);
        }
    }
    __threadfence();
    grid.sync();

    // ======== P1: kv partial accumulation (wave = head, block = 256-px chunk) ========
    {
        const int b = bid >> 6, ch = bid & 63;
        const int h = t >> 6, l = t & 63, g = l >> 4, m16 = l & 15;

        uint4* vlds4 = reinterpret_cast<uint4*>(smem);
        unsigned short* vlds = reinterpret_cast<unsigned short*>(smem);

        // stage 256 px x 64 c (fragment order)
        const float* vbase = v + ((size_t)b * NPIX + ch * 256) * 64;
#pragma unroll
        for (int i = 0; i < 4; ++i) {
            const int G = t + 512 * i;
            const int s = G >> 8, f = (G >> 6) & 3, ll = G & 63;
            const int mt = f >> 1, ks = f & 1, gg = ll >> 4, mm = ll & 15;
            const float* src = vbase + (size_t)(s * 32 + 16 * mt + mm) * 64 + 32 * ks + 8 * gg;
            const float4 a = *reinterpret_cast<const float4*>(src);
            const float4 c = *reinterpret_cast<const float4*>(src + 4);
            vlds4[G] = uint4{pk2(a.x, a.y), pk2(a.z, a.w), pk2(c.x, c.y), pk2(c.z, c.w)};
        }

        bhalf8 wkB[4][2], wvB[4][2], wks[2];
#pragma unroll
        for (int nt = 0; nt < 4; ++nt)
#pragma unroll
          for (int ks = 0; ks < 2; ++ks) {
              wkB[nt][ks] = *reinterpret_cast<const bhalf8*>(
                  wkpk + ((size_t)((h * 4 + nt) * 2 + ks)) * 512 + l * 8);
              wvB[nt][ks] = *reinterpret_cast<const bhalf8*>(
                  wvpk + ((size_t)((h * 4 + nt) * 2 + ks)) * 512 + l * 8);
          }
#pragma unroll
        for (int ks = 0; ks < 2; ++ks)
            wks[ks] = *reinterpret_cast<const bhalf8*>(wksumb + h * 64 + 32 * ks + 8 * g);

        float bksum;
        {
            float bl = bk[h * 64 + l];
#pragma unroll
            for (int m = 1; m < 64; m <<= 1) bl += __shfl_xor(bl, m, 64);
            bksum = bl;
        }
        float bkv[4], bvv[4];
#pragma unroll
        for (int nt = 0; nt < 4; ++nt) {
            bkv[nt] = bk[h * 64 + 16 * nt + m16];
            bvv[nt] = bv[h * 64 + 16 * nt + m16];
        }

        f32x4 kv[4][4];
#pragma unroll
        for (int i = 0; i < 4; ++i)
#pragma unroll
          for (int j = 0; j < 4; ++j) kv[i][j] = f32x4{0.f, 0.f, 0.f, 0.f};
        float tl[4] = {0.f, 0.f, 0.f, 0.f};
        float sv[4] = {0.f, 0.f, 0.f, 0.f};

        __syncthreads();

        for (int s = 0; s < 8; ++s) {
            bhalf8 vA[2][2];
#pragma unroll
            for (int mt = 0; mt < 2; ++mt)
#pragma unroll
              for (int ks = 0; ks < 2; ++ks)
                vA[mt][ks] = *reinterpret_cast<const bhalf8*>(
                    vlds + ((size_t)(s * 4 + mt * 2 + ks) * 64 + l) * 8);

            // K projection + bias
            f32x4 kq[2][4];
#pragma unroll
            for (int mt = 0; mt < 2; ++mt)
#pragma unroll
              for (int nt = 0; nt < 4; ++nt) {
                  f32x4 a = {0.f, 0.f, 0.f, 0.f};
                  a = MFMA_BF16(vA[mt][0], wkB[nt][0], a, 0, 0, 0);
                  a = MFMA_BF16(vA[mt][1], wkB[nt][1], a, 0, 0, 0);
#pragma unroll
                  for (int q = 0; q < 4; ++q) a[q] += bkv[nt];
                  kq[mt][nt] = a;
              }
            // s1 row-sum trick
            f32x4 st[2];
#pragma unroll
            for (int mt = 0; mt < 2; ++mt) {
                f32x4 a = {0.f, 0.f, 0.f, 0.f};
                a = MFMA_BF16(vA[mt][0], wks[0], a, 0, 0, 0);
                a = MFMA_BF16(vA[mt][1], wks[1], a, 0, 0, 0);
                st[mt] = a;
            }
            // s2 partial + m16-group butterfly
            f32x4 s2p[2];
#pragma unroll
            for (int mt = 0; mt < 2; ++mt)
#pragma unroll
              for (int q = 0; q < 4; ++q) {
                  float acc = kq[mt][0][q] * kq[mt][0][q];
                  acc = fmaf(kq[mt][1][q], kq[mt][1][q], acc);
                  acc = fmaf(kq[mt][2][q], kq[mt][2][q], acc);
                  acc = fmaf(kq[mt][3][q], kq[mt][3][q], acc);
                  s2p[mt][q] = acc;
              }
#pragma unroll
            for (int mt = 0; mt < 2; ++mt)
#pragma unroll
              for (int q = 0; q < 4; ++q) {
                  float x = s2p[mt][q];
                  x += __shfl_xor(x, 1, 64);
                  x += __shfl_xor(x, 2, 64);
                  x += __shfl_xor(x, 4, 64);
                  x += __shfl_xor(x, 8, 64);
                  s2p[mt][q] = x;
              }
            f32x4 rsv[2], cmu[2];
#pragma unroll
            for (int mt = 0; mt < 2; ++mt)
#pragma unroll
              for (int q = 0; q < 4; ++q) {
                  const float mu  = (st[mt][q] + bksum) * INV64;
                  const float var = s2p[mt][q] * INV64 - mu * mu;
                  const float rs  = rsqrtf(fmaxf(var, 0.f) + EPSV);
                  rsv[mt][q] = rs;
                  cmu[mt][q] = mu * rs;
              }
            // pack K~ (own registers)
            B8 ka[4];
#pragma unroll
            for (int MT = 0; MT < 4; ++MT) {
                ka[MT].u[0] = pk2(kq[0][MT][0] * rsv[0][0], kq[0][MT][1] * rsv[0][1]);
                ka[MT].u[1] = pk2(kq[0][MT][2] * rsv[0][2], kq[0][MT][3] * rsv[0][3]);
                ka[MT].u[2] = pk2(kq[1][MT][0] * rsv[1][0], kq[1][MT][1] * rsv[1][1]);
                ka[MT].u[3] = pk2(kq[1][MT][2] * rsv[1][2], kq[1][MT][3] * rsv[1][3]);
            }
            // V projection + bias
            f32x4 vq[2][4];
#pragma unroll
            for (int mt = 0; mt < 2; ++mt)
#pragma unroll
              for (int nt = 0; nt < 4; ++nt) {
                  f32x4 a = {0.f, 0.f, 0.f, 0.f};
                  a = MFMA_BF16(vA[mt][0], wvB[nt][0], a, 0, 0, 0);
                  a = MFMA_BF16(vA[mt][1], wvB[nt][1], a, 0, 0, 0);
#pragma unroll
                  for (int q = 0; q < 4; ++q) a[q] += bvv[nt];
                  vq[mt][nt] = a;
              }
            // t / Sv accumulation
#pragma unroll
            for (int nt = 0; nt < 4; ++nt) {
                float acc = tl[nt], acc2 = sv[nt];
#pragma unroll
                for (int mt = 0; mt < 2; ++mt)
#pragma unroll
                  for (int q = 0; q < 4; ++q) {
                      acc  = fmaf(cmu[mt][q], vq[mt][nt][q], acc);
                      acc2 += vq[mt][nt][q];
                  }
                tl[nt] = acc; sv[nt] = acc2;
            }
            // pack V' (own registers)
            B8 vb[4];
#pragma unroll
            for (int NT = 0; NT < 4; ++NT) {
                vb[NT].u[0] = pk2(vq[0][NT][0], vq[0][NT][1]);
                vb[NT].u[1] = pk2(vq[0][NT][2], vq[0][NT][3]);
                vb[NT].u[2] = pk2(vq[1][NT][0], vq[1][NT][1]);
                vb[NT].u[3] = pk2(vq[1][NT][2], vq[1][NT][3]);
            }
            // kv += K~^T V'
#pragma unroll
            for (int MT = 0; MT < 4; ++MT)
#pragma unroll
              for (int NT = 0; NT < 4; ++NT)
                  kv[MT][NT] = MFMA_BF16(ka[MT].v, vb[NT].v, kv[MT][NT], 0, 0, 0);
        }

        // reduce t/Sv over g lanes; write partial tile
#pragma unroll
        for (int nt = 0; nt < 4; ++nt) {
            float x = tl[nt];
            x += __shfl_xor(x, 16, 64); x += __shfl_xor(x, 32, 64);
            tl[nt] = x;
            float y = sv[nt];
            y += __shfl_xor(y, 16, 64); y += __shfl_xor(y, 32, 64);
            sv[nt] = y;
        }
        float* pdst = part + ((size_t)((b * NCH + ch) * 8 + h)) * TILE;
#pragma unroll
        for (int MT = 0; MT < 4; ++MT)
#pragma unroll
          for (int NT = 0; NT < 4; ++NT)
#pragma unroll
            for (int q = 0; q < 4; ++q)
                pdst[(16 * MT + 4 * g + q) * 64 + 16 * NT + m16] = kv[MT][NT][q];
        if (g == 0) {
#pragma unroll
            for (int nt = 0; nt < 4; ++nt) {
                pdst[64 * 64 + 16 * nt + m16] = tl[nt];
                pdst[65 * 64 + 16 * nt + m16] = sv[nt];
            }
        }
    }
    __threadfence();
    grid.sync();

    // ======== P2: partial reduce 8->1 (bid -> (bh, seg)) ========
    {
        const int bh = bid >> 3, seg = bid & 7;
        const int b = bh >> 3, hh = bh & 7;
        const float* base = part + ((size_t)((b * NCH + seg * 8) * 8 + hh)) * TILE;
        float* dst = s2buf + ((size_t)(bh * 8 + seg)) * TILE;
#pragma unroll
        for (int k = 0; k < 3; ++k) {
            const int idx = t + k * 512;              // float4 index, 1056 total
            if (idx < TILE / 4) {
                float4 s = make_float4(0.f, 0.f, 0.f, 0.f);
#pragma unroll
                for (int i = 0; i < 8; ++i) {
                    const float4 x = *reinterpret_cast<const float4*>(
                        base + (size_t)i * 8 * TILE + idx * 4);
                    s.x += x.x; s.y += x.y; s.z += x.z; s.w += x.w;
                }
                *reinterpret_cast<float4*>(dst + idx * 4) = s;
            }
        }
    }
    __threadfence();
    grid.sync();

    // ======== P3: mix (32 blocks; others pass through) ========
    if (bid < 32) {
        const int h = bid & 7, b = bid >> 3;
        float* kvs = smem;              // [64][65]
        float* wos = smem + 4160;       // [64][65]
        float* mls = smem + 8320;       // [64][65]
        float* Svs = smem + 12480;
        float* tds = smem + 12544;
        float* us  = smem + 12608;
        const float* sb = s2buf + ((size_t)((b * 8 + h) * 8)) * TILE;

        if (t < 256) {
            const int r = t >> 2, c0 = (t & 3) * 16;
            float acc[16];
#pragma unroll
            for (int i = 0; i < 16; ++i) acc[i] = 0.f;
#pragma unroll
            for (int seg = 0; seg < 8; ++seg) {
                const float* src = sb + (size_t)seg * TILE + r * 64 + c0;
#pragma unroll
                for (int q = 0; q < 4; ++q) {
                    const float4 x = *reinterpret_cast<const float4*>(src + 4 * q);
                    acc[4*q+0] += x.x; acc[4*q+1] += x.y; acc[4*q+2] += x.z; acc[4*q+3] += x.w;
                }
            }
#pragma unroll
            for (int i = 0; i < 16; ++i) kvs[r * 65 + c0 + i] = acc[i];
#pragma unroll
            for (int i = 0; i < 16; i += 4) {
                const float4 x = *reinterpret_cast<const float4*>(
                    Wo + ((size_t)(h * 64) + r) * 64 + c0 + i);
                wos[r * 65 + c0+i] = x.x; wos[r * 65 + c0+i+1] = x.y;
                wos[r * 65 + c0+i+2] = x.z; wos[r * 65 + c0+i+3] = x.w;
            }
        }
        if (t < 64) {
            float s = 0.f, s2 = 0.f;
#pragma unroll
            for (int seg = 0; seg < 8; ++seg) {
                s  += sb[(size_t)seg * TILE + 64 * 64 + t];
                s2 += sb[(size_t)seg * TILE + 65 * 64 + t];
            }
            tds[t] = s; Svs[t] = s2;
        }
        __syncthreads();
        if (t < 256) {
            const int r = t >> 2, c0 = (t & 3) * 16;
            const float gk = lnkg[h * 64 + r], bk2 = lnkb[h * 64 + r];
#pragma unroll
            for (int i = 0; i < 16; ++i) {
                const int e = c0 + i;
                kvs[r * 65 + e] = gk * (kvs[r * 65 + e] - tds[e]) + bk2 * Svs[e];
            }
        }
        __syncthreads();
        if (t < 64) {
            float s = 0.f;
            for (int dd = 0; dd < 64; ++dd) s = fmaf(lnqb[h * 64 + dd], kvs[dd * 65 + t], s);
            us[t] = s;
        }
        if (t < 256) {
            const int r = t >> 2, c0 = (t & 3) * 16;
            float mrow[16];
#pragma unroll
            for (int i = 0; i < 16; ++i) mrow[i] = 0.f;
            for (int e2 = 0; e2 < 64; ++e2) {
                const float kr = kvs[r * 65 + e2];
#pragma unroll
                for (int i = 0; i < 16; ++i) mrow[i] = fmaf(kr, wos[e2 * 65 + c0 + i], mrow[i]);
            }
            const float gq = lnqg[h * 64 + r] * INV_N;
#pragma unroll
            for (int i = 0; i < 16; ++i) mls[r * 65 + c0 + i] = gq * mrow[i];
        }
        __syncthreads();
        if (t < 64) {
            float s = 0.f;
            for (int e2 = 0; e2 < 64; ++e2) s = fmaf(us[e2], wos[e2 * 65 + t], s);
            cbh[(size_t)(b * 8 + h) * 64 + t] = s * INV_N;
        }
        if (t < 256) {
#pragma unroll
            for (int i = 0; i < 2; ++i) {
                const int f = t * 2 + i;
                const int nt = (f >> 7) & 3, ks = (f >> 6) & 1, l = f & 63;
                const int g = l >> 4, m = l & 15;
                unsigned short o[8];
#pragma unroll
                for (int j = 0; j < 8; ++j) {
                    const int d = 32 * ks + 16 * (j >> 2) + 4 * g + (j & 3);
                    o[j] = f2bf(mls[d * 65 + 16 * nt + m]);
                }
                unsigned short* dd = mpk + ((size_t)((b * 8 + h) * 8 + nt * 2 + ks)) * 512 + l * 8;
                *reinterpret_cast<ushort4*>(dd)     = make_ushort4(o[0], o[1], o[2], o[3]);
                *reinterpret_cast<ushort4*>(dd + 4) = make_ushort4(o[4], o[5], o[6], o[7]);
            }
        }
    }
    __threadfence();
    grid.sync();

    // ======== P4: Q projection + LN + out (wave = 32 px, same chunk as P1) ========
    {
        const int b = bid >> 6, ch = bid & 63;
        const int w = t >> 6, l = t & 63, g = l >> 4, m16 = l & 15;
        const size_t px0 = (size_t)b * NPIX + ch * 256 + w * 32;

        B8 vB[2][2];
#pragma unroll
        for (int nt = 0; nt < 2; ++nt)
#pragma unroll
          for (int ks = 0; ks < 2; ++ks) {
              const float* src = v + (px0 + 16 * nt + m16) * 64 + 32 * ks + 8 * g;
              const float4 a = *reinterpret_cast<const float4*>(src);
              const float4 c = *reinterpret_cast<const float4*>(src + 4);
              vB[nt][ks].u[0] = pk2(a.x, a.y); vB[nt][ks].u[1] = pk2(a.z, a.w);
              vB[nt][ks].u[2] = pk2(c.x, c.y); vB[nt][ks].u[3] = pk2(c.z, c.w);
          }
        float cbv[4];
#pragma unroll
        for (int nt = 0; nt < 4; ++nt) {
            const int e = 16 * nt + m16;
            float s = Wob[e] * INV_N;
#pragma unroll
            for (int h = 0; h < 8; ++h) s += cbh[(size_t)(b * 8 + h) * 64 + e];
            cbv[nt] = s;
        }

        f32x4 outa[2][4];
#pragma unroll
        for (int i = 0; i < 2; ++i)
#pragma unroll
          for (int j = 0; j < 4; ++j) outa[i][j] = f32x4{0.f, 0.f, 0.f, 0.f};

#pragma unroll
        for (int h = 0; h < 8; ++h) {
            bhalf8 wqA[4][2], mB[2][4];
#pragma unroll
            for (int mt = 0; mt < 4; ++mt)
#pragma unroll
              for (int ks = 0; ks < 2; ++ks)
                wqA[mt][ks] = *reinterpret_cast<const bhalf8*>(
                    wqpk + ((size_t)((h * 4 + mt) * 2 + ks)) * 512 + l * 8);
#pragma unroll
            for (int ks = 0; ks < 2; ++ks)
#pragma unroll
              for (int nt = 0; nt < 4; ++nt)
                mB[ks][nt] = *reinterpret_cast<const bhalf8*>(
                    mpk + ((size_t)((b * 8 + h) * 8 + nt * 2 + ks)) * 512 + l * 8);
            float4 bq4[4];
#pragma unroll
            for (int mt = 0; mt < 4; ++mt)
                bq4[mt] = *reinterpret_cast<const float4*>(bq + h * 64 + 16 * mt + 4 * g);

            f32x4 qa[4][2];
#pragma unroll
            for (int mt = 0; mt < 4; ++mt)
#pragma unroll
              for (int nt = 0; nt < 2; ++nt) {
                  f32x4 a = {0.f, 0.f, 0.f, 0.f};
                  a = MFMA_BF16(wqA[mt][0], vB[nt][0].v, a, 0, 0, 0);
                  a = MFMA_BF16(wqA[mt][1], vB[nt][1].v, a, 0, 0, 0);
                  a[0] += bq4[mt].x; a[1] += bq4[mt].y;
                  a[2] += bq4[mt].z; a[3] += bq4[mt].w;
                  qa[mt][nt] = a;
              }
            float mu[2], rs[2];
#pragma unroll
            for (int nt = 0; nt < 2; ++nt) {
                float s1 = 0.f, s2 = 0.f;
#pragma unroll
                for (int mt = 0; mt < 4; ++mt)
#pragma unroll
                  for (int q = 0; q < 4; ++q) {
                      const float x = qa[mt][nt][q];
                      s1 += x; s2 = fmaf(x, x, s2);
                  }
                s1 += __shfl_xor(s1, 16, 64); s1 += __shfl_xor(s1, 32, 64);
                s2 += __shfl_xor(s2, 16, 64); s2 += __shfl_xor(s2, 32, 64);
                mu[nt] = s1 * INV64;
                rs[nt] = rsqrtf(fmaxf(s2 * INV64 - mu[nt] * mu[nt], 0.f) + EPSV);
            }
            B8 ka[2][2];
#pragma unroll
            for (int MT = 0; MT < 2; ++MT)
#pragma unroll
              for (int ks = 0; ks < 2; ++ks) {
                  ka[MT][ks].u[0] = pk2((qa[2*ks+0][MT][0] - mu[MT]) * rs[MT],
                                        (qa[2*ks+0][MT][1] - mu[MT]) * rs[MT]);
                  ka[MT][ks].u[1] = pk2((qa[2*ks+0][MT][2] - mu[MT]) * rs[MT],
                                        (qa[2*ks+0][MT][3] - mu[MT]) * rs[MT]);
                  ka[MT][ks].u[2] = pk2((qa[2*ks+1][MT][0] - mu[MT]) * rs[MT],
                                        (qa[2*ks+1][MT][1] - mu[MT]) * rs[MT]);
                  ka[MT][ks].u[3] = pk2((qa[2*ks+1][MT][2] - mu[MT]) * rs[MT],
                                        (qa[2*ks+1][MT][3] - mu[MT]) * rs[MT]);
              }
#pragma unroll
            for (int MT = 0; MT < 2; ++MT)
#pragma unroll
              for (int nt = 0; nt < 4; ++nt) {
                  outa[MT][nt] = MFMA_BF16(ka[MT][0].v, mB[0][nt], outa[MT][nt], 0, 0, 0);
                  outa[MT][nt] = MFMA_BF16(ka[MT][1].v, mB[1][nt], outa[MT][nt], 0, 0, 0);
              }
        }

#pragma unroll
        for (int MT = 0; MT < 2; ++MT)
#pragma unroll
          for (int q = 0; q < 4; ++q) {
              float* orow = out + (px0 + 16 * MT + 4 * g + q) * 64;
#pragma unroll
              for (int nt = 0; nt < 4; ++nt)
                  orow[16 * nt + m16] = outa[MT][nt][q] + cbv[nt];
          }
    }
}

} // namespace

extern "C" void kernel_launch(void* const* d_in, const int* in_sizes, int n_in,
                              void* d_out, int out_size, void* d_ws, size_t ws_size,
                              hipStream_t stream)
{
    const float* v     = (const float*)d_in[0];
    const float* Wq_w  = (const float*)d_in[1];
    const float* Wq_b  = (const float*)d_in[2];
    const float* Wk_w  = (const float*)d_in[3];
    const float* Wk_b  = (const float*)d_in[4];
    const float* Wv_w  = (const float*)d_in[5];
    const float* Wv_b  = (const float*)d_in[6];
    const float* lnq_g = (const float*)d_in[7];
    const float* lnq_b = (const float*)d_in[8];
    const float* lnk_g = (const float*)d_in[9];
    const float* lnk_b = (const float*)d_in[10];
    const float* Wo_w  = (const float*)d_in[11];
    const float* Wo_b  = (const float*)d_in[12];
    float* out = (float*)d_out;

    float* wsf    = (float*)d_ws;
    float* part   = wsf;                                      // 4*64*8*TILE
    float* s2buf  = part + (size_t)4 * NCH * 8 * TILE;        // 32*8*TILE
    float* cbh    = s2buf + (size_t)32 * 8 * TILE;            // 2048
    unsigned short* base_s = (unsigned short*)(cbh + 2048);
    unsigned short* wkpk   = base_s;
    unsigned short* wvpk   = base_s + 32768;
    unsigned short* wqpk   = base_s + 65536;
    unsigned short* wksumb = base_s + 98304;
    unsigned short* mpk    = base_s + 98816;

    void* args[] = {
        (void*)&v,
        (void*)&Wq_w, (void*)&Wq_b,
        (void*)&Wk_w, (void*)&Wk_b,
        (void*)&Wv_w, (void*)&Wv_b,
        (void*)&lnq_g, (void*)&lnq_b,
        (void*)&lnk_g, (void*)&lnk_b,
        (void*)&Wo_w, (void*)&Wo_b,
        (void*)&out,
        (void*)&part, (void*)&s2buf, (void*)&cbh,
        (void*)&wkpk, (void*)&wvpk, (void*)&wqpk, (void*)&wksumb, (void*)&mpk
    };
    hipLaunchCooperativeKernel(fused, dim3(256), dim3(512), args, 0, stream);
}

// Round 8
// 185.542 us; speedup vs baseline: 2.5814x; 2.5814x over previous
//
#include <hip/hip_runtime.h>
#include <hip/hip_bf16.h>

typedef __attribute__((ext_vector_type(8))) short bhalf8;
typedef __attribute__((ext_vector_type(4))) float f32x4;

#define MFMA_BF16 __builtin_amdgcn_mfma_f32_16x16x32_bf16

namespace {

constexpr int   NPIX  = 16384;
constexpr int   NCH   = 64;          // 256-px chunks per batch
constexpr int   TILE  = 66 * 64;     // partial tile: 64 kv rows + t row + Sv row
constexpr float EPSV  = 1e-5f;
constexpr float INV64 = 1.0f / 64.0f;
constexpr float INV_N = 1.0f / 16384.0f;

__device__ __forceinline__ unsigned short f2bf(float f) {
    unsigned int u = __builtin_bit_cast(unsigned int, f);
    u += 0x7fffu + ((u >> 16) & 1u);
    return (unsigned short)(u >> 16);
}

union B8 { bhalf8 v; unsigned int u[4]; };

__device__ __forceinline__ unsigned int pk2(float a, float b) {
    union { __hip_bfloat162 h; unsigned int u; } x;
    x.h = __float22bfloat162_rn(float2{a, b});
    return x.u;
}

// ---------------------------------------------------------------------------
// prep: pack weight fragments (bf16) + wksum rows. grid 24 x 256.
// ---------------------------------------------------------------------------
__global__ void prep(const float* __restrict__ Wk, const float* __restrict__ Wv,
                     const float* __restrict__ Wq,
                     unsigned short* __restrict__ wkpk, unsigned short* __restrict__ wvpk,
                     unsigned short* __restrict__ wqpk, unsigned short* __restrict__ wksumb)
{
    const int w = blockIdx.x >> 3, h = blockIdx.x & 7, t = threadIdx.x;
    const float* W = (w == 0) ? Wk : (w == 1) ? Wv : Wq;
    unsigned short* dst = (w == 0) ? wkpk : (w == 1) ? wvpk : wqpk;

#pragma unroll
    for (int i = 0; i < 2; ++i) {
        const int f = t * 2 + i;
        const int nt = (f >> 7) & 3, ks = (f >> 6) & 1, l = f & 63;
        const int g = l >> 4, m = l & 15;
        unsigned short tmp[8];
#pragma unroll
        for (int j = 0; j < 8; ++j)
            tmp[j] = f2bf(W[(size_t)(32 * ks + 8 * g + j) * 512 + h * 64 + 16 * nt + m]);
        unsigned short* d = dst + ((size_t)((h * 4 + nt) * 2 + ks)) * 512 + l * 8;
        *reinterpret_cast<ushort4*>(d)     = make_ushort4(tmp[0], tmp[1], tmp[2], tmp[3]);
        *reinterpret_cast<ushort4*>(d + 4) = make_ushort4(tmp[4], tmp[5], tmp[6], tmp[7]);
    }
    if (w == 0 && t < 64) {
        float s = 0.f;
        const float* row = Wk + (size_t)t * 512 + h * 64;
#pragma unroll
        for (int d = 0; d < 64; ++d) s += row[d];
        wksumb[h * 64 + t] = f2bf(s);
    }
}

// ---------------------------------------------------------------------------
// ka: block = (chunk of 256 px, b), 8 waves; wave = head. v staged once to
// LDS in fragment order; K/V proj (bias via MFMA C-init), LN-fold, kv in
// registers (permuted k-slot map); writes per-chunk partial tile [66][64].
// ---------------------------------------------------------------------------
__global__ __launch_bounds__(512, 2)
void ka_kv(const float* __restrict__ v,
           const unsigned short* __restrict__ wkpk, const unsigned short* __restrict__ wvpk,
           const unsigned short* __restrict__ wksumb,
           const float* __restrict__ bk, const float* __restrict__ bv,
           float* __restrict__ part)
{
    const int ch = blockIdx.x, b = blockIdx.y;
    const int t = threadIdx.x, h = t >> 6, l = t & 63, g = l >> 4, m16 = l & 15;

    __shared__ uint4 vlds4[2048];                       // 32 KB, fragment-ordered
    unsigned short* vlds = reinterpret_cast<unsigned short*>(vlds4);

    const float* vbase = v + ((size_t)b * NPIX + ch * 256) * 64;
#pragma unroll
    for (int i = 0; i < 4; ++i) {
        const int G = t + 512 * i;
        const int s = G >> 8, f = (G >> 6) & 3, ll = G & 63;
        const int mt = f >> 1, ks = f & 1, gg = ll >> 4, mm = ll & 15;
        const float* src = vbase + (size_t)(s * 32 + 16 * mt + mm) * 64 + 32 * ks + 8 * gg;
        const float4 a = *reinterpret_cast<const float4*>(src);
        const float4 c = *reinterpret_cast<const float4*>(src + 4);
        vlds4[G] = uint4{pk2(a.x, a.y), pk2(a.z, a.w), pk2(c.x, c.y), pk2(c.z, c.w)};
    }

    bhalf8 wkB[4][2], wvB[4][2], wks[2];
#pragma unroll
    for (int nt = 0; nt < 4; ++nt)
#pragma unroll
      for (int ks = 0; ks < 2; ++ks) {
          wkB[nt][ks] = *reinterpret_cast<const bhalf8*>(
              wkpk + ((size_t)((h * 4 + nt) * 2 + ks)) * 512 + l * 8);
          wvB[nt][ks] = *reinterpret_cast<const bhalf8*>(
              wvpk + ((size_t)((h * 4 + nt) * 2 + ks)) * 512 + l * 8);
      }
#pragma unroll
    for (int ks = 0; ks < 2; ++ks)
        wks[ks] = *reinterpret_cast<const bhalf8*>(wksumb + h * 64 + 32 * ks + 8 * g);

    float bksum;
    {
        float bl = bk[h * 64 + l];
#pragma unroll
        for (int m = 1; m < 64; m <<= 1) bl += __shfl_xor(bl, m, 64);
        bksum = bl;
    }
    float bkv[4], bvv[4];
#pragma unroll
    for (int nt = 0; nt < 4; ++nt) {
        bkv[nt] = bk[h * 64 + 16 * nt + m16];
        bvv[nt] = bv[h * 64 + 16 * nt + m16];
    }

    f32x4 kv[4][4];
#pragma unroll
    for (int i = 0; i < 4; ++i)
#pragma unroll
      for (int j = 0; j < 4; ++j) kv[i][j] = f32x4{0.f, 0.f, 0.f, 0.f};
    float tl[4] = {0.f, 0.f, 0.f, 0.f};
    float sv[4] = {0.f, 0.f, 0.f, 0.f};

    __syncthreads();

    for (int s = 0; s < 8; ++s) {
        bhalf8 vA[2][2];
#pragma unroll
        for (int mt = 0; mt < 2; ++mt)
#pragma unroll
          for (int ks = 0; ks < 2; ++ks)
            vA[mt][ks] = *reinterpret_cast<const bhalf8*>(
                vlds + ((size_t)(s * 4 + mt * 2 + ks) * 64 + l) * 8);

        // K projection, bias via C-init (C: px=16mt+4g+q, d=16nt+m16)
        f32x4 kq[2][4];
#pragma unroll
        for (int mt = 0; mt < 2; ++mt)
#pragma unroll
          for (int nt = 0; nt < 4; ++nt) {
              f32x4 a = {bkv[nt], bkv[nt], bkv[nt], bkv[nt]};
              a = MFMA_BF16(vA[mt][0], wkB[nt][0], a, 0, 0, 0);
              a = MFMA_BF16(vA[mt][1], wkB[nt][1], a, 0, 0, 0);
              kq[mt][nt] = a;
          }
        // s1 row-sum trick
        f32x4 st[2];
#pragma unroll
        for (int mt = 0; mt < 2; ++mt) {
            f32x4 a = {0.f, 0.f, 0.f, 0.f};
            a = MFMA_BF16(vA[mt][0], wks[0], a, 0, 0, 0);
            a = MFMA_BF16(vA[mt][1], wks[1], a, 0, 0, 0);
            st[mt] = a;
        }
        // s2 partial + m16-group butterfly
        f32x4 s2p[2];
#pragma unroll
        for (int mt = 0; mt < 2; ++mt)
#pragma unroll
          for (int q = 0; q < 4; ++q) {
              float acc = kq[mt][0][q] * kq[mt][0][q];
              acc = fmaf(kq[mt][1][q], kq[mt][1][q], acc);
              acc = fmaf(kq[mt][2][q], kq[mt][2][q], acc);
              acc = fmaf(kq[mt][3][q], kq[mt][3][q], acc);
              s2p[mt][q] = acc;
          }
#pragma unroll
        for (int mt = 0; mt < 2; ++mt)
#pragma unroll
          for (int q = 0; q < 4; ++q) {
              float x = s2p[mt][q];
              x += __shfl_xor(x, 1, 64);
              x += __shfl_xor(x, 2, 64);
              x += __shfl_xor(x, 4, 64);
              x += __shfl_xor(x, 8, 64);
              s2p[mt][q] = x;
          }
        f32x4 rsv[2], cmu[2];
#pragma unroll
        for (int mt = 0; mt < 2; ++mt)
#pragma unroll
          for (int q = 0; q < 4; ++q) {
              const float mu  = (st[mt][q] + bksum) * INV64;
              const float var = s2p[mt][q] * INV64 - mu * mu;
              const float rs  = rsqrtf(fmaxf(var, 0.f) + EPSV);
              rsv[mt][q] = rs;
              cmu[mt][q] = mu * rs;
          }
        // pack K~ = rs*K (own registers)
        B8 ka[4];
#pragma unroll
        for (int MT = 0; MT < 4; ++MT) {
            ka[MT].u[0] = pk2(kq[0][MT][0] * rsv[0][0], kq[0][MT][1] * rsv[0][1]);
            ka[MT].u[1] = pk2(kq[0][MT][2] * rsv[0][2], kq[0][MT][3] * rsv[0][3]);
            ka[MT].u[2] = pk2(kq[1][MT][0] * rsv[1][0], kq[1][MT][1] * rsv[1][1]);
            ka[MT].u[3] = pk2(kq[1][MT][2] * rsv[1][2], kq[1][MT][3] * rsv[1][3]);
        }
        // V projection, bias via C-init
        f32x4 vq[2][4];
#pragma unroll
        for (int mt = 0; mt < 2; ++mt)
#pragma unroll
          for (int nt = 0; nt < 4; ++nt) {
              f32x4 a = {bvv[nt], bvv[nt], bvv[nt], bvv[nt]};
              a = MFMA_BF16(vA[mt][0], wvB[nt][0], a, 0, 0, 0);
              a = MFMA_BF16(vA[mt][1], wvB[nt][1], a, 0, 0, 0);
              vq[mt][nt] = a;
          }
        // t / Sv accumulation
#pragma unroll
        for (int nt = 0; nt < 4; ++nt) {
            float acc = tl[nt], acc2 = sv[nt];
#pragma unroll
            for (int mt = 0; mt < 2; ++mt)
#pragma unroll
              for (int q = 0; q < 4; ++q) {
                  acc  = fmaf(cmu[mt][q], vq[mt][nt][q], acc);
                  acc2 += vq[mt][nt][q];
              }
            tl[nt] = acc; sv[nt] = acc2;
        }
        // pack V' (own registers)
        B8 vb[4];
#pragma unroll
        for (int NT = 0; NT < 4; ++NT) {
            vb[NT].u[0] = pk2(vq[0][NT][0], vq[0][NT][1]);
            vb[NT].u[1] = pk2(vq[0][NT][2], vq[0][NT][3]);
            vb[NT].u[2] = pk2(vq[1][NT][0], vq[1][NT][1]);
            vb[NT].u[3] = pk2(vq[1][NT][2], vq[1][NT][3]);
        }
        // kv += K~^T V'
#pragma unroll
        for (int MT = 0; MT < 4; ++MT)
#pragma unroll
          for (int NT = 0; NT < 4; ++NT)
              kv[MT][NT] = MFMA_BF16(ka[MT].v, vb[NT].v, kv[MT][NT], 0, 0, 0);
    }

    // reduce t/Sv over g lanes; write partial tile
#pragma unroll
    for (int nt = 0; nt < 4; ++nt) {
        float x = tl[nt];
        x += __shfl_xor(x, 16, 64); x += __shfl_xor(x, 32, 64);
        tl[nt] = x;
        float y = sv[nt];
        y += __shfl_xor(y, 16, 64); y += __shfl_xor(y, 32, 64);
        sv[nt] = y;
    }
    float* pdst = part + ((size_t)((b * NCH + ch) * 8 + h)) * TILE;
#pragma unroll
    for (int MT = 0; MT < 4; ++MT)
#pragma unroll
      for (int NT = 0; NT < 4; ++NT)
#pragma unroll
        for (int q = 0; q < 4; ++q)
            pdst[(16 * MT + 4 * g + q) * 64 + 16 * NT + m16] = kv[MT][NT][q];
    if (g == 0) {
#pragma unroll
        for (int nt = 0; nt < 4; ++nt) {
            pdst[64 * 64 + 16 * nt + m16] = tl[nt];
            pdst[65 * 64 + 16 * nt + m16] = sv[nt];
        }
    }
}

// ---------------------------------------------------------------------------
// mix: per (h,b): reduce 64 chunk partials (8x8 tree), kvF = gk*(kv - t)
//  + bk (x) Sv; M = kvF @ Wo_h; mpk = frag-packed gq*M/n; cbh = bq^T M / n.
// ---------------------------------------------------------------------------
__global__ void mix(const float* __restrict__ part,
                    const float* __restrict__ lnkg, const float* __restrict__ lnkb,
                    const float* __restrict__ lnqg, const float* __restrict__ lnqb,
                    const float* __restrict__ Wo,   const float* __restrict__ Wob,
                    unsigned short* __restrict__ mpk, float* __restrict__ cbh)
{
    const int h = blockIdx.x, b = blockIdx.y, t = threadIdx.x;
    __shared__ float kvs[64][65], wos[64][65], mls[64][65], Svs[64], tds[64], us[64];
    const int r = t >> 2, c0 = (t & 3) * 16;
    const float* pb = part + ((size_t)(b * NCH * 8 + h)) * TILE;

    float acc[16];
#pragma unroll
    for (int i = 0; i < 16; ++i) acc[i] = 0.f;
    for (int s8 = 0; s8 < 8; ++s8) {
        float tmp[16];
#pragma unroll
        for (int i = 0; i < 16; ++i) tmp[i] = 0.f;
#pragma unroll
        for (int i8 = 0; i8 < 8; ++i8) {
            const float* src = pb + (size_t)(s8 * 8 + i8) * 8 * TILE + r * 64 + c0;
#pragma unroll
            for (int q = 0; q < 4; ++q) {
                const float4 x = *reinterpret_cast<const float4*>(src + 4 * q);
                tmp[4*q+0] += x.x; tmp[4*q+1] += x.y; tmp[4*q+2] += x.z; tmp[4*q+3] += x.w;
            }
        }
#pragma unroll
        for (int i = 0; i < 16; ++i) acc[i] += tmp[i];
    }
#pragma unroll
    for (int i = 0; i < 16; ++i) kvs[r][c0 + i] = acc[i];

    if (t < 64) {
        float s = 0.f, s2 = 0.f;
        for (int s8 = 0; s8 < 8; ++s8) {
            float a1 = 0.f, a2 = 0.f;
#pragma unroll
            for (int i8 = 0; i8 < 8; ++i8) {
                const float* src = pb + (size_t)(s8 * 8 + i8) * 8 * TILE;
                a1 += src[64 * 64 + t];
                a2 += src[65 * 64 + t];
            }
            s += a1; s2 += a2;
        }
        tds[t] = s; Svs[t] = s2;
    }
#pragma unroll
    for (int i = 0; i < 16; i += 4) {
        const float4 x = *reinterpret_cast<const float4*>(
            Wo + ((size_t)(h * 64) + r) * 64 + c0 + i);
        wos[r][c0+i] = x.x; wos[r][c0+i+1] = x.y; wos[r][c0+i+2] = x.z; wos[r][c0+i+3] = x.w;
    }
    __syncthreads();
    {
        const float gk = lnkg[h * 64 + r], bk2 = lnkb[h * 64 + r];
#pragma unroll
        for (int i = 0; i < 16; ++i) {
            const int e = c0 + i;
            kvs[r][e] = gk * (kvs[r][e] - tds[e]) + bk2 * Svs[e];
        }
    }
    __syncthreads();
    if (t < 64) {
        float s = 0.f;
        for (int dd = 0; dd < 64; ++dd) s = fmaf(lnqb[h * 64 + dd], kvs[dd][t], s);
        us[t] = s;
    }
    float mrow[16];
#pragma unroll
    for (int i = 0; i < 16; ++i) mrow[i] = 0.f;
    for (int e2 = 0; e2 < 64; ++e2) {
        const float kr = kvs[r][e2];
#pragma unroll
        for (int i = 0; i < 16; ++i) mrow[i] = fmaf(kr, wos[e2][c0 + i], mrow[i]);
    }
    {
        const float gq = lnqg[h * 64 + r] * INV_N;
#pragma unroll
        for (int i = 0; i < 16; ++i) mls[r][c0 + i] = gq * mrow[i];
    }
    __syncthreads();
    if (t < 64) {
        float s = 0.f;
        for (int e2 = 0; e2 < 64; ++e2) s = fmaf(us[e2], wos[e2][t], s);
        cbh[(size_t)(b * 8 + h) * 64 + t] = s * INV_N;
    }
    // frag-packed M' with permuted k-slot map d = 32ks+16(j>>2)+4g+(j&3)
#pragma unroll
    for (int i = 0; i < 2; ++i) {
        const int f = t * 2 + i;
        const int nt = (f >> 7) & 3, ks = (f >> 6) & 1, l = f & 63;
        const int g = l >> 4, m = l & 15;
        unsigned short o[8];
#pragma unroll
        for (int j = 0; j < 8; ++j) {
            const int d = 32 * ks + 16 * (j >> 2) + 4 * g + (j & 3);
            o[j] = f2bf(mls[d][16 * nt + m]);
        }
        unsigned short* dd = mpk + ((size_t)((b * 8 + h) * 8 + nt * 2 + ks)) * 512 + l * 8;
        *reinterpret_cast<ushort4*>(dd)     = make_ushort4(o[0], o[1], o[2], o[3]);
        *reinterpret_cast<ushort4*>(dd + 4) = make_ushort4(o[4], o[5], o[6], o[7]);
    }
}

// ---------------------------------------------------------------------------
// k3: wave = 32 px; fully-unrolled head loop; bias via MFMA C-init;
// cbh rows summed in epilogue (deterministic).
// ---------------------------------------------------------------------------
__global__ __launch_bounds__(256, 2)
void k3_out(const float* __restrict__ v,
            const unsigned short* __restrict__ wqpk, const float* __restrict__ bq,
            const unsigned short* __restrict__ mpk,  const float* __restrict__ cbh,
            const float* __restrict__ Wob, float* __restrict__ out)
{
    const int blk = blockIdx.x, b = blockIdx.y;
    const int t = threadIdx.x, w = t >> 6, l = t & 63, g = l >> 4, m16 = l & 15;
    const size_t px0 = (size_t)b * NPIX + blk * 128 + w * 32;

    B8 vB[2][2];
#pragma unroll
    for (int nt = 0; nt < 2; ++nt)
#pragma unroll
      for (int ks = 0; ks < 2; ++ks) {
          const float* src = v + (px0 + 16 * nt + m16) * 64 + 32 * ks + 8 * g;
          const float4 a = *reinterpret_cast<const float4*>(src);
          const float4 c = *reinterpret_cast<const float4*>(src + 4);
          vB[nt][ks].u[0] = pk2(a.x, a.y); vB[nt][ks].u[1] = pk2(a.z, a.w);
          vB[nt][ks].u[2] = pk2(c.x, c.y); vB[nt][ks].u[3] = pk2(c.z, c.w);
      }
    float cbv[4];
#pragma unroll
    for (int nt = 0; nt < 4; ++nt) {
        const int e = 16 * nt + m16;
        float s = Wob[e] * INV_N;
#pragma unroll
        for (int h = 0; h < 8; ++h) s += cbh[(size_t)(b * 8 + h) * 64 + e];
        cbv[nt] = s;
    }

    f32x4 outa[2][4];
#pragma unroll
    for (int i = 0; i < 2; ++i)
#pragma unroll
      for (int j = 0; j < 4; ++j) outa[i][j] = f32x4{0.f, 0.f, 0.f, 0.f};

#pragma unroll
    for (int h = 0; h < 8; ++h) {
        bhalf8 wqA[4][2], mB[2][4];
#pragma unroll
        for (int mt = 0; mt < 4; ++mt)
#pragma unroll
          for (int ks = 0; ks < 2; ++ks)
            wqA[mt][ks] = *reinterpret_cast<const bhalf8*>(
                wqpk + ((size_t)((h * 4 + mt) * 2 + ks)) * 512 + l * 8);
#pragma unroll
        for (int ks = 0; ks < 2; ++ks)
#pragma unroll
          for (int nt = 0; nt < 4; ++nt)
            mB[ks][nt] = *reinterpret_cast<const bhalf8*>(
                mpk + ((size_t)((b * 8 + h) * 8 + nt * 2 + ks)) * 512 + l * 8);
        float4 bq4[4];
#pragma unroll
        for (int mt = 0; mt < 4; ++mt)
            bq4[mt] = *reinterpret_cast<const float4*>(bq + h * 64 + 16 * mt + 4 * g);

        // Q^T projection, bias via C-init (C: d=16mt+4g+q, px=16nt+m16)
        f32x4 qa[4][2];
#pragma unroll
        for (int mt = 0; mt < 4; ++mt)
#pragma unroll
          for (int nt = 0; nt < 2; ++nt) {
              f32x4 a = {bq4[mt].x, bq4[mt].y, bq4[mt].z, bq4[mt].w};
              a = MFMA_BF16(wqA[mt][0], vB[nt][0].v, a, 0, 0, 0);
              a = MFMA_BF16(wqA[mt][1], vB[nt][1].v, a, 0, 0, 0);
              qa[mt][nt] = a;
          }
        float mu[2], rs[2];
#pragma unroll
        for (int nt = 0; nt < 2; ++nt) {
            float s1 = 0.f, s2 = 0.f;
#pragma unroll
            for (int mt = 0; mt < 4; ++mt)
#pragma unroll
              for (int q = 0; q < 4; ++q) {
                  const float x = qa[mt][nt][q];
                  s1 += x; s2 = fmaf(x, x, s2);
              }
            s1 += __shfl_xor(s1, 16, 64); s1 += __shfl_xor(s1, 32, 64);
            s2 += __shfl_xor(s2, 16, 64); s2 += __shfl_xor(s2, 32, 64);
            mu[nt] = s1 * INV64;
            rs[nt] = rsqrtf(fmaxf(s2 * INV64 - mu[nt] * mu[nt], 0.f) + EPSV);
        }
        B8 ka[2][2];
#pragma unroll
        for (int MT = 0; MT < 2; ++MT)
#pragma unroll
          for (int ks = 0; ks < 2; ++ks) {
              ka[MT][ks].u[0] = pk2((qa[2*ks+0][MT][0] - mu[MT]) * rs[MT],
                                    (qa[2*ks+0][MT][1] - mu[MT]) * rs[MT]);
              ka[MT][ks].u[1] = pk2((qa[2*ks+0][MT][2] - mu[MT]) * rs[MT],
                                    (qa[2*ks+0][MT][3] - mu[MT]) * rs[MT]);
              ka[MT][ks].u[2] = pk2((qa[2*ks+1][MT][0] - mu[MT]) * rs[MT],
                                    (qa[2*ks+1][MT][1] - mu[MT]) * rs[MT]);
              ka[MT][ks].u[3] = pk2((qa[2*ks+1][MT][2] - mu[MT]) * rs[MT],
                                    (qa[2*ks+1][MT][3] - mu[MT]) * rs[MT]);
          }
#pragma unroll
        for (int MT = 0; MT < 2; ++MT)
#pragma unroll
          for (int nt = 0; nt < 4; ++nt) {
              outa[MT][nt] = MFMA_BF16(ka[MT][0].v, mB[0][nt], outa[MT][nt], 0, 0, 0);
              outa[MT][nt] = MFMA_BF16(ka[MT][1].v, mB[1][nt], outa[MT][nt], 0, 0, 0);
          }
    }

#pragma unroll
    for (int MT = 0; MT < 2; ++MT)
#pragma unroll
      for (int q = 0; q < 4; ++q) {
          float* orow = out + (px0 + 16 * MT + 4 * g + q) * 64;
#pragma unroll
          for (int nt = 0; nt < 4; ++nt)
              orow[16 * nt + m16] = outa[MT][nt][q] + cbv[nt];
      }
}

} // namespace

extern "C" void kernel_launch(void* const* d_in, const int* in_sizes, int n_in,
                              void* d_out, int out_size, void* d_ws, size_t ws_size,
                              hipStream_t stream)
{
    const float* v     = (const float*)d_in[0];
    const float* Wq_w  = (const float*)d_in[1];
    const float* Wq_b  = (const float*)d_in[2];
    const float* Wk_w  = (const float*)d_in[3];
    const float* Wk_b  = (const float*)d_in[4];
    const float* Wv_w  = (const float*)d_in[5];
    const float* Wv_b  = (const float*)d_in[6];
    const float* lnq_g = (const float*)d_in[7];
    const float* lnq_b = (const float*)d_in[8];
    const float* lnk_g = (const float*)d_in[9];
    const float* lnk_b = (const float*)d_in[10];
    const float* Wo_w  = (const float*)d_in[11];
    const float* Wo_b  = (const float*)d_in[12];
    float* out = (float*)d_out;

    float* wsf    = (float*)d_ws;
    float* part   = wsf;                                      // 4*64*8*TILE floats
    float* cbh    = part + (size_t)4 * NCH * 8 * TILE;        // 2048 floats
    unsigned short* base_s = (unsigned short*)(cbh + 2048);
    unsigned short* wkpk   = base_s;
    unsigned short* wvpk   = base_s + 32768;
    unsigned short* wqpk   = base_s + 65536;
    unsigned short* wksumb = base_s + 98304;
    unsigned short* mpk    = base_s + 98816;

    prep<<<24, 256, 0, stream>>>(Wk_w, Wv_w, Wq_w, wkpk, wvpk, wqpk, wksumb);
    ka_kv<<<dim3(NCH, 4), 512, 0, stream>>>(v, wkpk, wvpk, wksumb, Wk_b, Wv_b, part);
    mix<<<dim3(8, 4), 256, 0, stream>>>(part, lnk_g, lnk_b, lnq_g, lnq_b,
                                        Wo_w, Wo_b, mpk, cbh);
    k3_out<<<dim3(128, 4), 256, 0, stream>>>(v, wqpk, Wq_b, mpk, cbh, Wo_b, out);
}